// Round 5
// baseline (1271.554 us; speedup 1.0000x reference)
//
#include <hip/hip_runtime.h>
#include <stdint.h>

#define B_    128
#define S_    256
#define EMB_  300
#define HID_  256
#define TAGS_ 50
#define KPAD  320           // EMB padded to multiple of 32
#define NROWS (B_ * S_)     // 32768, row r = s*128 + b
#define GF    (4 * HID_)    // 1024 gate cols per direction
#define NCOLS (2 * GF)      // 2048 (fwd | bwd)

typedef __bf16 bf16x8 __attribute__((ext_vector_type(8)));
typedef float  f32x4  __attribute__((ext_vector_type(4)));
typedef unsigned int u32x4 __attribute__((ext_vector_type(4)));
typedef unsigned long long u64x2 __attribute__((ext_vector_type(2)));

__device__ __forceinline__ unsigned short f2bf(float f) {
    unsigned int u = __float_as_uint(f);
    unsigned int r = (u + 0x7fffu + ((u >> 16) & 1u)) >> 16;  // RNE
    return (unsigned short)r;
}
__device__ __forceinline__ bf16x8 ldb8(const unsigned short* p) {
    u32x4 v = *reinterpret_cast<const u32x4*>(p);
    return __builtin_bit_cast(bf16x8, v);
}
__device__ __forceinline__ float sigmoidf_fast(float x) {
    return 1.0f / (1.0f + __expf(-x));
}

// sign-bit tag patterns (h >= 0 always, so data sign bits are free):
// epoch0: elems 0,2 negated; epoch1: elems 0,3. Poison 0xAA.. has ALL four
// sign bits set, unwritten garbage is overwhelmingly unlikely to match, and
// the two epochs are mutually distinct -> data IS the flag.
#define SGNMASK 0x8000800080008000ULL
#define EXP0    0x0000800000008000ULL
#define EXP1    0x8000000000008000ULL

// ---------------- K0a: embedding gather -> bf16, K-padded -------------------
__global__ void k_gather_x(const int* __restrict__ tokens, const float* __restrict__ emb,
                           unsigned short* __restrict__ X16) {
    int r = blockIdx.x;            // r = s*128 + b
    int k = threadIdx.x;           // 0..319
    int b = r & 127, s = r >> 7;
    int tok = tokens[b * S_ + s];
    float v = (k < EMB_) ? emb[(long)tok * EMB_ + k] : 0.0f;
    X16[(long)r * KPAD + k] = f2bf(v);
}

// ---------------- K0b: Wx (f|b) -> transposed bf16 [2048][320] --------------
__global__ void k_prep_w(const float* __restrict__ Wx_f, const float* __restrict__ Wx_b,
                         unsigned short* __restrict__ W16T) {
    int c = blockIdx.x;            // 0..2047
    int k = threadIdx.x;           // 0..319
    float v = 0.0f;
    if (k < EMB_) v = (c < GF) ? Wx_f[k * GF + c] : Wx_b[k * GF + (c - GF)];
    W16T[c * KPAD + k] = f2bf(v);
}

// ---------------- K0c: Wd -> transposed bf16 [64][512] ----------------------
__global__ void k_prep_wd(const float* __restrict__ Wd, unsigned short* __restrict__ WdT16) {
    int c = blockIdx.x;            // 0..63
    int k = threadIdx.x;           // 0..511
    float v = (c < TAGS_) ? Wd[k * TAGS_ + c] : 0.0f;
    WdT16[c * 512 + k] = f2bf(v);
}

// ---------------- K0d: Wh -> packed bf16 [2 dir][4 slice][256 c][256 k] -----
__global__ void k_prep_wh(const float* __restrict__ Wh_f, const float* __restrict__ Wh_b,
                          unsigned short* __restrict__ WhP) {
    int row = blockIdx.x;          // 0..2047 = (d*4+sl)*256 + c
    int k = threadIdx.x;           // 0..255
    int d = row >> 10, sl = (row >> 8) & 3, c = row & 255;
    int gate = c >> 6, jrel = c & 63;
    const float* Wh = d ? Wh_b : Wh_f;
    WhP[(long)row * 256 + k] = f2bf(Wh[k * GF + gate * HID_ + sl * 64 + jrel]);
}

// ---------------- K1: xz = X @ Wx + b  (MFMA, LDS-free) ---------------------
__global__ __launch_bounds__(256) void k_gemm_xz(
    const unsigned short* __restrict__ X16, const unsigned short* __restrict__ W16T,
    const float* __restrict__ b_f, const float* __restrict__ b_b,
    unsigned long long* __restrict__ xzP) {
    int w = threadIdx.x >> 6, lane = threadIdx.x & 63;
    int quad = lane >> 4, l16 = lane & 15;
    int m0 = blockIdx.x * 128 + w * 32;
    int n0 = blockIdx.y * 128;
    f32x4 acc[2][8];
#pragma unroll
    for (int mt = 0; mt < 2; ++mt)
#pragma unroll
        for (int nt = 0; nt < 8; ++nt) acc[mt][nt] = (f32x4){0.f, 0.f, 0.f, 0.f};

    int koff = quad * 8;
#pragma unroll
    for (int ks = 0; ks < 10; ++ks) {
        int k0 = ks * 32 + koff;
        bf16x8 a[2], bb[8];
#pragma unroll
        for (int mt = 0; mt < 2; ++mt)
            a[mt] = ldb8(X16 + (long)(m0 + mt * 16 + l16) * KPAD + k0);
#pragma unroll
        for (int nt = 0; nt < 8; ++nt)
            bb[nt] = ldb8(W16T + (long)(n0 + nt * 16 + l16) * KPAD + k0);
#pragma unroll
        for (int mt = 0; mt < 2; ++mt)
#pragma unroll
            for (int nt = 0; nt < 8; ++nt)
                acc[mt][nt] = __builtin_amdgcn_mfma_f32_16x16x32_bf16(a[mt], bb[nt], acc[mt][nt], 0, 0, 0);
    }
    int s = blockIdx.x;            // m>>7
#pragma unroll
    for (int mt = 0; mt < 2; ++mt) {
        int grp = w * 2 + mt;      // (b>>4)
#pragma unroll
        for (int nt = 0; nt < 8; ++nt) {
            int col = n0 + nt * 16 + l16;
            int dir = col >> 10, cc = col & 1023;
            int gate = cc >> 8, j = cc & 255;
            int sl = j >> 6, wv = (j >> 4) & 3;
            float bias = dir ? b_b[cc] : b_f[cc];
            unsigned long long pk = 0;
#pragma unroll
            for (int r = 0; r < 4; ++r)
                pk |= (unsigned long long)f2bf(acc[mt][nt][r] + bias) << (16 * r);
            long idx8 = ((((long)s * 16 + (dir * 8 + grp)) * 4 + sl) * 4 + wv) * 256 + lane * 4 + gate;
            xzP[idx8] = pk;
        }
    }
}

// ---------------- K2: bidirectional LSTM recurrence -------------------------
// 64 blocks = 2 dir x 8 batch-groups(16) x 4 j-slices. Wh register-resident.
// Cross-block exchange: per-lane 8B agent-scope atomic stores where the DATA
// carries the readiness tag in spare sign bits (h>=0). No counters, no RMWs,
// no fences, no vmcnt-draining barrier on the publish path. Ring of 64 slots
// per group with epoch-parity tags (wave skew provably <=1 step).
__global__ __launch_bounds__(256, 1) void k_recurrence(
    const unsigned short* __restrict__ WhP, const unsigned long long* __restrict__ xzP,
    unsigned short* __restrict__ hcat16, unsigned long long* __restrict__ hbuf) {
    int tid = threadIdx.x;
    int w = tid >> 6, lane = tid & 63, quad = lane >> 4, l16 = lane & 15;
    int blk = blockIdx.x;
    int d = blk >> 5, g = (blk >> 2) & 7, sl = blk & 3;
    int g16 = d * 8 + g;
    int widx = sl * 4 + w;         // wave's 16-unit slice: units 16*widx..+15

    // persistent Wh B-fragments: whf[gate][kt], 128 VGPR/lane
    bf16x8 whf[4][8];
    const unsigned short* whp = WhP + (long)((d * 4 + sl) * 256) * 256;
#pragma unroll
    for (int gate = 0; gate < 4; ++gate)
#pragma unroll
        for (int kt = 0; kt < 8; ++kt)
            whf[gate][kt] = ldb8(whp + (gate * 64 + 16 * w + l16) * 256 + kt * 32 + quad * 8);

    unsigned long long* grp = hbuf + (long)g16 * 64 * 1024;  // 64 slots x [16 b][64 u64]

    __shared__ __align__(16) unsigned short tile[4][256];    // per-wave 16x16 transpose
    unsigned short* myt = tile[w];
    float c4[4] = {0.f, 0.f, 0.f, 0.f};

    int pb = lane >> 2, pch = lane & 3;   // producer role: batch pb, 4-unit chunk pch
    long hcat_addr = ((long)(g * 16 + pb) * S_) * 512 + d * HID_ + widx * 16 + pch * 4;

    for (int t = 0; t < 256; ++t) {
        int s = d ? (255 - t) : t;
        // xz fragment (plain cached load, issued before the poll)
        long base8 = ((((long)s * 16 + g16) * 4 + sl) * 4 + w) * 256 + lane * 4;
        u32x4 xza = *reinterpret_cast<const u32x4*>(xzP + base8);
        u32x4 xzb = *reinterpret_cast<const u32x4*>(xzP + base8 + 2);

        f32x4 acc[4];
#pragma unroll
        for (int gate = 0; gate < 4; ++gate) acc[gate] = (f32x4){0.f, 0.f, 0.f, 0.f};

        if (t > 0) {
            int pslot = (t - 1) & 63;
            unsigned long long expd = ((t - 1) & 64) ? EXP1 : EXP0;
            const unsigned long long* hp = grp + (long)pslot * 1024 + l16 * 64 + quad * 2;
            unsigned long long hv[16];
            for (;;) {
#pragma unroll
                for (int kt = 0; kt < 8; ++kt) {
                    hv[2 * kt]     = __hip_atomic_load(hp + kt * 8,     __ATOMIC_RELAXED, __HIP_MEMORY_SCOPE_AGENT);
                    hv[2 * kt + 1] = __hip_atomic_load(hp + kt * 8 + 1, __ATOMIC_RELAXED, __HIP_MEMORY_SCOPE_AGENT);
                }
                bool okl = true;
#pragma unroll
                for (int i = 0; i < 16; ++i) okl &= ((hv[i] & SGNMASK) == expd);
                if (__all(okl)) break;
            }
#pragma unroll
            for (int i = 0; i < 16; ++i) hv[i] &= ~expd;
#pragma unroll
            for (int kt = 0; kt < 8; ++kt) {
                u64x2 pr;
                pr[0] = hv[2 * kt];
                pr[1] = hv[2 * kt + 1];
                bf16x8 a = __builtin_bit_cast(bf16x8, pr);
#pragma unroll
                for (int gate = 0; gate < 4; ++gate)
                    acc[gate] = __builtin_amdgcn_mfma_f32_16x16x32_bf16(a, whf[gate][kt], acc[gate], 0, 0, 0);
            }
        }
        // gates: lane holds batches 4*quad..+3, unit j = 16*widx + l16
        unsigned int xr[8];
        *reinterpret_cast<u32x4*>(xr) = xza;
        *reinterpret_cast<u32x4*>(xr + 4) = xzb;
#pragma unroll
        for (int r = 0; r < 4; ++r) {
            int hi = (r & 1) * 16;
            float zi = acc[0][r] + __uint_as_float(((xr[0 + (r >> 1)] >> hi) & 0xffffu) << 16);
            float zf = acc[1][r] + __uint_as_float(((xr[2 + (r >> 1)] >> hi) & 0xffffu) << 16);
            float zg = acc[2][r] + __uint_as_float(((xr[4 + (r >> 1)] >> hi) & 0xffffu) << 16);
            float zo = acc[3][r] + __uint_as_float(((xr[6 + (r >> 1)] >> hi) & 0xffffu) << 16);
            float c = sigmoidf_fast(zf) * c4[r] + sigmoidf_fast(zi) * fmaxf(zg, 0.0f);
            c4[r] = c;
            float h = sigmoidf_fast(zo) * fmaxf(c, 0.0f);
            myt[(4 * quad + r) * 16 + l16] = f2bf(h);   // [batch][unit-in-tile]
        }
        __syncthreads();   // orders the wave-local LDS transpose (cheap: no hot stores outstanding)
        // publish: lane (pb,pch) -> u64 = h[pb][units 16*widx+4*pch .. +3], tagged
        unsigned long long hd = *reinterpret_cast<unsigned long long*>(myt + pb * 16 + pch * 4);
        *reinterpret_cast<unsigned long long*>(hcat16 + hcat_addr + (long)s * 512) = hd;
        unsigned long long tag = (t & 64) ? EXP1 : EXP0;
        __hip_atomic_store(grp + (long)(t & 63) * 1024 + pb * 64 + widx * 4 + pch, hd | tag,
                           __ATOMIC_RELAXED, __HIP_MEMORY_SCOPE_AGENT);
    }
}

// ---------------- K3: logits = hcat @ Wd  (MFMA, N padded to 64) ------------
__global__ __launch_bounds__(256) void k_gemm_logits(
    const unsigned short* __restrict__ hcat16, const unsigned short* __restrict__ WdT16,
    float* __restrict__ logits) {
    int w = threadIdx.x >> 6, lane = threadIdx.x & 63;
    int quad = lane >> 4, l16 = lane & 15;
    int m0 = blockIdx.x * 128 + w * 32;
    f32x4 acc[2][4];
#pragma unroll
    for (int mt = 0; mt < 2; ++mt)
#pragma unroll
        for (int nt = 0; nt < 4; ++nt) acc[mt][nt] = (f32x4){0.f, 0.f, 0.f, 0.f};
#pragma unroll
    for (int ks = 0; ks < 16; ++ks) {
        int k0 = ks * 32 + quad * 8;
        bf16x8 a[2], bb[4];
#pragma unroll
        for (int mt = 0; mt < 2; ++mt)
            a[mt] = ldb8(hcat16 + (long)(m0 + mt * 16 + l16) * 512 + k0);
#pragma unroll
        for (int nt = 0; nt < 4; ++nt)
            bb[nt] = ldb8(WdT16 + (long)(nt * 16 + l16) * 512 + k0);
#pragma unroll
        for (int mt = 0; mt < 2; ++mt)
#pragma unroll
            for (int nt = 0; nt < 4; ++nt)
                acc[mt][nt] = __builtin_amdgcn_mfma_f32_16x16x32_bf16(a[mt], bb[nt], acc[mt][nt], 0, 0, 0);
    }
#pragma unroll
    for (int mt = 0; mt < 2; ++mt)
#pragma unroll
        for (int nt = 0; nt < 4; ++nt) {
            int rbase = m0 + mt * 16 + quad * 4;
            int col = nt * 16 + l16;
#pragma unroll
            for (int r = 0; r < 4; ++r)
                logits[(long)(rbase + r) * 64 + col] = acc[mt][nt][r];
        }
}

// ---------------- K4: +bd, softmax over 50 tags (one wave per row) ----------
__global__ __launch_bounds__(256) void k_softmax(const float* __restrict__ logits,
                                                 const float* __restrict__ bd,
                                                 float* __restrict__ out) {
    int w = threadIdx.x >> 6, lane = threadIdx.x & 63;
    long r = (long)blockIdx.x * 4 + w;
    float x = (lane < TAGS_) ? logits[r * 64 + lane] + bd[lane] : -3.0e38f;
    float m = x;
#pragma unroll
    for (int off = 32; off >= 1; off >>= 1) m = fmaxf(m, __shfl_xor(m, off, 64));
    float e = (lane < TAGS_) ? __expf(x - m) : 0.0f;
    float ssum = e;
#pragma unroll
    for (int off = 32; off >= 1; off >>= 1) ssum += __shfl_xor(ssum, off, 64);
    if (lane < TAGS_) out[r * TAGS_ + lane] = e / ssum;
}

extern "C" void kernel_launch(void* const* d_in, const int* in_sizes, int n_in,
                              void* d_out, int out_size, void* d_ws, size_t ws_size,
                              hipStream_t stream) {
    (void)in_sizes; (void)n_in; (void)out_size; (void)ws_size;
    const int*   tokens = (const int*)  d_in[0];
    const float* emb    = (const float*)d_in[1];
    const float* Wx_f   = (const float*)d_in[2];
    const float* Wh_f   = (const float*)d_in[3];
    const float* b_f    = (const float*)d_in[4];
    const float* Wx_b   = (const float*)d_in[5];
    const float* Wh_b   = (const float*)d_in[6];
    const float* b_b    = (const float*)d_in[7];
    const float* Wd     = (const float*)d_in[8];
    const float* bd     = (const float*)d_in[9];
    float* out = (float*)d_out;

    // workspace layout (bytes): total 190,119,936
    uint8_t* w = (uint8_t*)d_ws;
    unsigned short* X16    = (unsigned short*)(w);                  // 20,971,520 (dead after K1)
    // aliases inside X16's region, used only after K1:
    unsigned short* WhP    = (unsigned short*)(w);                  //  1,048,576
    unsigned long long* hbuf = (unsigned long long*)(w + 1048576);  //  8,388,608 (ring; self-validating tags, no init)
    unsigned short* W16T   = (unsigned short*)(w + 20971520);       //  1,310,720
    unsigned short* WdT16  = (unsigned short*)(w + 22282240);       //     65,536
    unsigned long long* xzP = (unsigned long long*)(w + 22347776);  // 134,217,728
    unsigned short* hcat16 = (unsigned short*)(w + 156565504);      //  33,554,432
    float*          logits = (float*)(w + 22347776);                // alias xzP (dead after K2)

    k_gather_x  <<<dim3(NROWS),     dim3(KPAD), 0, stream>>>(tokens, emb, X16);
    k_prep_w    <<<dim3(NCOLS),     dim3(KPAD), 0, stream>>>(Wx_f, Wx_b, W16T);
    k_prep_wd   <<<dim3(64),        dim3(512),  0, stream>>>(Wd, WdT16);
    k_gemm_xz   <<<dim3(256, 16),   dim3(256),  0, stream>>>(X16, W16T, b_f, b_b, xzP);
    // X16 region now dead -> build WhP in it (hbuf needs no init: tag-validated)
    k_prep_wh   <<<dim3(2048),      dim3(256),  0, stream>>>(Wh_f, Wh_b, WhP);
    k_recurrence<<<dim3(64),        dim3(256),  0, stream>>>(WhP, xzP, hcat16, hbuf);
    k_gemm_logits<<<dim3(256),      dim3(256),  0, stream>>>(hcat16, WdT16, logits);
    k_softmax   <<<dim3(NROWS / 4), dim3(256),  0, stream>>>(logits, bd, out);
}

// Round 6
// 1197.033 us; speedup vs baseline: 1.0623x; 1.0623x over previous
//
#include <hip/hip_runtime.h>
#include <stdint.h>

#define B_    128
#define S_    256
#define EMB_  300
#define HID_  256
#define TAGS_ 50
#define KPAD  320           // EMB padded to multiple of 32
#define NROWS (B_ * S_)     // 32768, row r = s*128 + b
#define GF    (4 * HID_)    // 1024 gate cols per direction
#define NCOLS (2 * GF)      // 2048 (fwd | bwd)

typedef __bf16 bf16x8 __attribute__((ext_vector_type(8)));
typedef float  f32x4  __attribute__((ext_vector_type(4)));
typedef unsigned int u32x4 __attribute__((ext_vector_type(4)));

__device__ __forceinline__ unsigned short f2bf(float f) {
    unsigned int u = __float_as_uint(f);
    unsigned int r = (u + 0x7fffu + ((u >> 16) & 1u)) >> 16;  // RNE
    return (unsigned short)r;
}
__device__ __forceinline__ bf16x8 ldb8(const unsigned short* p) {
    u32x4 v = *reinterpret_cast<const u32x4*>(p);
    return __builtin_bit_cast(bf16x8, v);
}
__device__ __forceinline__ float sigmoidf_fast(float x) {
    return 1.0f / (1.0f + __expf(-x));
}

// ---------------- K0a: embedding gather -> bf16, K-padded -------------------
__global__ void k_gather_x(const int* __restrict__ tokens, const float* __restrict__ emb,
                           unsigned short* __restrict__ X16) {
    int r = blockIdx.x;            // r = s*128 + b
    int k = threadIdx.x;           // 0..319
    int b = r & 127, s = r >> 7;
    int tok = tokens[b * S_ + s];
    float v = (k < EMB_) ? emb[(long)tok * EMB_ + k] : 0.0f;
    X16[(long)r * KPAD + k] = f2bf(v);
}

// ---------------- K0b: Wx (f|b) -> transposed bf16 [2048][320] --------------
__global__ void k_prep_w(const float* __restrict__ Wx_f, const float* __restrict__ Wx_b,
                         unsigned short* __restrict__ W16T) {
    int c = blockIdx.x;            // 0..2047
    int k = threadIdx.x;           // 0..319
    float v = 0.0f;
    if (k < EMB_) v = (c < GF) ? Wx_f[k * GF + c] : Wx_b[k * GF + (c - GF)];
    W16T[c * KPAD + k] = f2bf(v);
}

// ---------------- K0c: Wd -> transposed bf16 [64][512] ----------------------
__global__ void k_prep_wd(const float* __restrict__ Wd, unsigned short* __restrict__ WdT16) {
    int c = blockIdx.x;            // 0..63
    int k = threadIdx.x;           // 0..511
    float v = (c < TAGS_) ? Wd[k * TAGS_ + c] : 0.0f;
    WdT16[c * 512 + k] = f2bf(v);
}

// ---------------- K0d: Wh -> packed bf16 [2 dir][4 sl][256 c][256 k] --------
// (only gate-2 (g) rows are consumed by the recurrence now; kept full/simple)
__global__ void k_prep_wh(const float* __restrict__ Wh_f, const float* __restrict__ Wh_b,
                          unsigned short* __restrict__ WhP) {
    int row = blockIdx.x;          // 0..2047 = (d*4+sl)*256 + c
    int k = threadIdx.x;           // 0..255
    int d = row >> 10, sl = (row >> 8) & 3, c = row & 255;
    int gate = c >> 6, jrel = c & 63;
    const float* Wh = d ? Wh_b : Wh_f;
    WhP[(long)row * 256 + k] = f2bf(Wh[k * GF + gate * HID_ + sl * 64 + jrel]);
}

// ---------------- K0e: Wh gates i,f,o -> fp8 e4m3 [2 dir][3 g][256 j][256 k]-
__global__ void k_prep_wh8(const float* __restrict__ Wh_f, const float* __restrict__ Wh_b,
                           unsigned char* __restrict__ WhP8) {
    int row = blockIdx.x;          // 0..1535 = (d*3+gi)*256 + j
    int k = threadIdx.x;           // 0..255
    int d = row / 768, rr = row - d * 768, gi = rr >> 8, j = rr & 255;
    int ga = (gi == 2) ? 3 : gi;   // i=0, f=1, o=3
    const float* Wh = d ? Wh_b : Wh_f;
    float v = Wh[k * GF + ga * HID_ + j];
    int p = __builtin_amdgcn_cvt_pk_fp8_f32(v, 0.0f, 0, false);
    WhP8[(long)row * 256 + k] = (unsigned char)(p & 0xff);
}

// ---------------- K1: xz = X @ Wx + b  (MFMA, LDS-free) ---------------------
// u64 index = (((s*16 + g16)*16 + u16)*256 + lane*4 + gate, lane = quad*16+l16
__global__ __launch_bounds__(256) void k_gemm_xz(
    const unsigned short* __restrict__ X16, const unsigned short* __restrict__ W16T,
    const float* __restrict__ b_f, const float* __restrict__ b_b,
    unsigned long long* __restrict__ xzP) {
    int w = threadIdx.x >> 6, lane = threadIdx.x & 63;
    int quad = lane >> 4, l16 = lane & 15;
    int m0 = blockIdx.x * 128 + w * 32;
    int n0 = blockIdx.y * 128;
    f32x4 acc[2][8];
#pragma unroll
    for (int mt = 0; mt < 2; ++mt)
#pragma unroll
        for (int nt = 0; nt < 8; ++nt) acc[mt][nt] = (f32x4){0.f, 0.f, 0.f, 0.f};

    int koff = quad * 8;
#pragma unroll
    for (int ks = 0; ks < 10; ++ks) {
        int k0 = ks * 32 + koff;
        bf16x8 a[2], bb[8];
#pragma unroll
        for (int mt = 0; mt < 2; ++mt)
            a[mt] = ldb8(X16 + (long)(m0 + mt * 16 + l16) * KPAD + k0);
#pragma unroll
        for (int nt = 0; nt < 8; ++nt)
            bb[nt] = ldb8(W16T + (long)(n0 + nt * 16 + l16) * KPAD + k0);
#pragma unroll
        for (int mt = 0; mt < 2; ++mt)
#pragma unroll
            for (int nt = 0; nt < 8; ++nt)
                acc[mt][nt] = __builtin_amdgcn_mfma_f32_16x16x32_bf16(a[mt], bb[nt], acc[mt][nt], 0, 0, 0);
    }
    int s = blockIdx.x;            // m>>7
#pragma unroll
    for (int mt = 0; mt < 2; ++mt) {
        int grp = w * 2 + mt;      // (b>>4)
#pragma unroll
        for (int nt = 0; nt < 8; ++nt) {
            int col = n0 + nt * 16 + l16;
            int dir = col >> 10, cc = col & 1023;
            int gate = cc >> 8, j = cc & 255;
            int u16 = j >> 4;
            float bias = dir ? b_b[cc] : b_f[cc];
            unsigned long long pk = 0;
#pragma unroll
            for (int r = 0; r < 4; ++r)
                pk |= (unsigned long long)f2bf(acc[mt][nt][r] + bias) << (16 * r);
            long idx8 = (((long)s * 16 + (dir * 8 + grp)) * 16 + u16) * 256 + lane * 4 + gate;
            xzP[idx8] = pk;
        }
    }
}

// ---------------- K2: bidirectional LSTM recurrence, SINGLE-CU chains -------
// 16 blocks = 2 dir x 8 batch-groups(16). 512 threads = 8 waves, 2 waves/SIMD.
// Wh fully register-resident per CU: gate g (relu candidate, feeds c) in bf16
// (sensitive), gates i/f/o in fp8 e4m3 (errors don't accumulate in c).
// h exchanged through XOR-swizzled LDS double buffers; ONE barrier per step.
__global__ __launch_bounds__(512, 2) void k_recurrence(
    const unsigned short* __restrict__ WhP, const unsigned char* __restrict__ WhP8,
    const unsigned long long* __restrict__ xzP, unsigned short* __restrict__ hcat16) {
    int tid = threadIdx.x;
    int widx = tid >> 6, lane = tid & 63, quad = lane >> 4, l16 = lane & 15;
    int blk = blockIdx.x;
    int d = blk >> 3, g = blk & 7;
    int g16 = d * 8 + g;

    // persistent Wh fragments. wave widx owns unit-groups u16 = 2*widx + {0,1}
    bf16x8 whg[2][8];                   // gate 2 (g), bf16: 64 VGPR
    unsigned long long wh8[3][2][8];    // gates i,f,o fp8: 96 VGPR
#pragma unroll
    for (int g2 = 0; g2 < 2; ++g2) {
        int u16g = widx * 2 + g2;
        int sl = u16g >> 2, wv = u16g & 3;
        const unsigned short* wp = WhP + ((long)((d * 4 + sl) * 256 + 128 + wv * 16 + l16)) * 256;
#pragma unroll
        for (int kt = 0; kt < 8; ++kt)
            whg[g2][kt] = ldb8(wp + kt * 32 + quad * 8);
#pragma unroll
        for (int gi = 0; gi < 3; ++gi) {
            const unsigned char* wp8 = WhP8 + ((long)((d * 3 + gi) * 256 + u16g * 16 + l16)) * 256;
#pragma unroll
            for (int kt = 0; kt < 8; ++kt)
                wh8[gi][g2][kt] = *reinterpret_cast<const unsigned long long*>(wp8 + kt * 32 + quad * 8);
        }
    }

    // LDS h double buffers, XOR-swizzled: elem (b,u) at b*256 + ((u>>3)^(b&7))*8 + (u&7)
    __shared__ __align__(16) unsigned short hb[2][4096];  // bf16, 16 KB
    __shared__ __align__(16) unsigned char  h8[2][4096];  // fp8 e4m3, 8 KB

    float c4[2][4] = {{0.f, 0.f, 0.f, 0.f}, {0.f, 0.f, 0.f, 0.f}};
    int l7 = l16 & 7;

    for (int t = 0; t < 256; ++t) {
        int s = d ? (255 - t) : t;
        int pbuf = t & 1, cbuf = 1 - pbuf;
        // prefetch xz for both unit-groups (long-latency global loads)
        u32x4 xzl[2][2];
#pragma unroll
        for (int g2 = 0; g2 < 2; ++g2) {
            long base8 = (((long)s * 16 + g16) * 16 + (2 * widx + g2)) * 256 + lane * 4;
            xzl[g2][0] = *reinterpret_cast<const u32x4*>(xzP + base8);
            xzl[g2][1] = *reinterpret_cast<const u32x4*>(xzP + base8 + 2);
        }
#pragma unroll
        for (int g2 = 0; g2 < 2; ++g2) {
            f32x4 ai = (f32x4){0.f, 0.f, 0.f, 0.f};
            f32x4 af = ai, ag = ai, ao = ai;
            if (t > 0) {
#pragma unroll
                for (int kt = 0; kt < 8; ++kt) {
                    int ch = (kt * 4 + quad) ^ l7;
                    bf16x8 A = ldb8(&hb[cbuf][l16 * 256 + ch * 8]);
                    long A8 = *reinterpret_cast<const long*>(&h8[cbuf][l16 * 256 + ch * 8]);
                    ag = __builtin_amdgcn_mfma_f32_16x16x32_bf16(A, whg[g2][kt], ag, 0, 0, 0);
                    ai = __builtin_amdgcn_mfma_f32_16x16x32_fp8_fp8(A8, (long)wh8[0][g2][kt], ai, 0, 0, 0);
                    af = __builtin_amdgcn_mfma_f32_16x16x32_fp8_fp8(A8, (long)wh8[1][g2][kt], af, 0, 0, 0);
                    ao = __builtin_amdgcn_mfma_f32_16x16x32_fp8_fp8(A8, (long)wh8[2][g2][kt], ao, 0, 0, 0);
                }
            }
            unsigned int xr[8];
            *reinterpret_cast<u32x4*>(xr) = xzl[g2][0];
            *reinterpret_cast<u32x4*>(xr + 4) = xzl[g2][1];
            float hq[4];
#pragma unroll
            for (int r = 0; r < 4; ++r) {
                int hi = (r & 1) * 16;
                float zi = ai[r] + __uint_as_float(((xr[0 + (r >> 1)] >> hi) & 0xffffu) << 16);
                float zf = af[r] + __uint_as_float(((xr[2 + (r >> 1)] >> hi) & 0xffffu) << 16);
                float zg = ag[r] + __uint_as_float(((xr[4 + (r >> 1)] >> hi) & 0xffffu) << 16);
                float zo = ao[r] + __uint_as_float(((xr[6 + (r >> 1)] >> hi) & 0xffffu) << 16);
                float c = sigmoidf_fast(zf) * c4[g2][r] + sigmoidf_fast(zi) * fmaxf(zg, 0.0f);
                c4[g2][r] = c;
                hq[r] = sigmoidf_fast(zo) * fmaxf(c, 0.0f);
            }
            unsigned int pk = __builtin_amdgcn_cvt_pk_fp8_f32(hq[0], hq[1], 0, false);
            pk = (unsigned int)__builtin_amdgcn_cvt_pk_fp8_f32(hq[2], hq[3], (int)pk, true);
            int u3 = 2 * (2 * widx + g2) + (l16 >> 3);   // (u>>3)
#pragma unroll
            for (int r = 0; r < 4; ++r) {
                int b = 4 * quad + r;
                int off = b * 256 + ((u3 ^ (b & 7))) * 8 + l7;
                hb[pbuf][off] = f2bf(hq[r]);
                h8[pbuf][off] = (unsigned char)((pk >> (8 * r)) & 0xffu);
            }
        }
        __syncthreads();
        // coalesced hcat write from the completed buffer (2 u64 per thread)
#pragma unroll
        for (int e = 0; e < 2; ++e) {
            int cidx = tid + e * 512;
            int b = cidx >> 6, c64 = cidx & 63;
            int off = b * 256 + (((c64 >> 1) ^ (b & 7))) * 8 + (c64 & 1) * 4;
            unsigned long long hv = *reinterpret_cast<const unsigned long long*>(&hb[pbuf][off]);
            *reinterpret_cast<unsigned long long*>(
                hcat16 + ((long)(g * 16 + b) * S_ + s) * 512 + d * HID_ + c64 * 4) = hv;
        }
    }
}

// ---------------- K3: logits = hcat @ Wd  (MFMA, N padded to 64) ------------
__global__ __launch_bounds__(256) void k_gemm_logits(
    const unsigned short* __restrict__ hcat16, const unsigned short* __restrict__ WdT16,
    float* __restrict__ logits) {
    int w = threadIdx.x >> 6, lane = threadIdx.x & 63;
    int quad = lane >> 4, l16 = lane & 15;
    int m0 = blockIdx.x * 128 + w * 32;
    f32x4 acc[2][4];
#pragma unroll
    for (int mt = 0; mt < 2; ++mt)
#pragma unroll
        for (int nt = 0; nt < 4; ++nt) acc[mt][nt] = (f32x4){0.f, 0.f, 0.f, 0.f};
#pragma unroll
    for (int ks = 0; ks < 16; ++ks) {
        int k0 = ks * 32 + quad * 8;
        bf16x8 a[2], bb[4];
#pragma unroll
        for (int mt = 0; mt < 2; ++mt)
            a[mt] = ldb8(hcat16 + (long)(m0 + mt * 16 + l16) * 512 + k0);
#pragma unroll
        for (int nt = 0; nt < 4; ++nt)
            bb[nt] = ldb8(WdT16 + (long)(nt * 16 + l16) * 512 + k0);
#pragma unroll
        for (int mt = 0; mt < 2; ++mt)
#pragma unroll
            for (int nt = 0; nt < 4; ++nt)
                acc[mt][nt] = __builtin_amdgcn_mfma_f32_16x16x32_bf16(a[mt], bb[nt], acc[mt][nt], 0, 0, 0);
    }
#pragma unroll
    for (int mt = 0; mt < 2; ++mt)
#pragma unroll
        for (int nt = 0; nt < 4; ++nt) {
            int rbase = m0 + mt * 16 + quad * 4;
            int col = nt * 16 + l16;
#pragma unroll
            for (int r = 0; r < 4; ++r)
                logits[(long)(rbase + r) * 64 + col] = acc[mt][nt][r];
        }
}

// ---------------- K4: +bd, softmax over 50 tags (one wave per row) ----------
__global__ __launch_bounds__(256) void k_softmax(const float* __restrict__ logits,
                                                 const float* __restrict__ bd,
                                                 float* __restrict__ out) {
    int w = threadIdx.x >> 6, lane = threadIdx.x & 63;
    long r = (long)blockIdx.x * 4 + w;
    float x = (lane < TAGS_) ? logits[r * 64 + lane] + bd[lane] : -3.0e38f;
    float m = x;
#pragma unroll
    for (int off = 32; off >= 1; off >>= 1) m = fmaxf(m, __shfl_xor(m, off, 64));
    float e = (lane < TAGS_) ? __expf(x - m) : 0.0f;
    float ssum = e;
#pragma unroll
    for (int off = 32; off >= 1; off >>= 1) ssum += __shfl_xor(ssum, off, 64);
    if (lane < TAGS_) out[r * TAGS_ + lane] = e / ssum;
}

extern "C" void kernel_launch(void* const* d_in, const int* in_sizes, int n_in,
                              void* d_out, int out_size, void* d_ws, size_t ws_size,
                              hipStream_t stream) {
    (void)in_sizes; (void)n_in; (void)out_size; (void)ws_size;
    const int*   tokens = (const int*)  d_in[0];
    const float* emb    = (const float*)d_in[1];
    const float* Wx_f   = (const float*)d_in[2];
    const float* Wh_f   = (const float*)d_in[3];
    const float* b_f    = (const float*)d_in[4];
    const float* Wx_b   = (const float*)d_in[5];
    const float* Wh_b   = (const float*)d_in[6];
    const float* b_b    = (const float*)d_in[7];
    const float* Wd     = (const float*)d_in[8];
    const float* bd     = (const float*)d_in[9];
    float* out = (float*)d_out;

    // workspace layout (bytes): total 190,119,936
    uint8_t* w = (uint8_t*)d_ws;
    unsigned short* X16    = (unsigned short*)(w);                  // 20,971,520 (dead after K1)
    // aliases inside X16's region, used only after K1:
    unsigned short* WhP    = (unsigned short*)(w);                  //  1,048,576
    unsigned char*  WhP8   = (unsigned char*)(w + 1048576);         //    393,216
    unsigned short* W16T   = (unsigned short*)(w + 20971520);       //  1,310,720
    unsigned short* WdT16  = (unsigned short*)(w + 22282240);       //     65,536
    unsigned long long* xzP = (unsigned long long*)(w + 22347776);  // 134,217,728
    unsigned short* hcat16 = (unsigned short*)(w + 156565504);      //  33,554,432
    float*          logits = (float*)(w + 22347776);                // alias xzP (dead after K2)

    k_gather_x  <<<dim3(NROWS),     dim3(KPAD), 0, stream>>>(tokens, emb, X16);
    k_prep_w    <<<dim3(NCOLS),     dim3(KPAD), 0, stream>>>(Wx_f, Wx_b, W16T);
    k_prep_wd   <<<dim3(64),        dim3(512),  0, stream>>>(Wd, WdT16);
    k_gemm_xz   <<<dim3(256, 16),   dim3(256),  0, stream>>>(X16, W16T, b_f, b_b, xzP);
    // X16 region now dead -> build WhP / WhP8 in it
    k_prep_wh   <<<dim3(2048),      dim3(256),  0, stream>>>(Wh_f, Wh_b, WhP);
    k_prep_wh8  <<<dim3(1536),      dim3(256),  0, stream>>>(Wh_f, Wh_b, WhP8);
    k_recurrence<<<dim3(16),        dim3(512),  0, stream>>>(WhP, WhP8, xzP, hcat16);
    k_gemm_logits<<<dim3(256),      dim3(256),  0, stream>>>(hcat16, WdT16, logits);
    k_softmax   <<<dim3(NROWS / 4), dim3(256),  0, stream>>>(logits, bd, out);
}

// Round 7
// 860.950 us; speedup vs baseline: 1.4769x; 1.3904x over previous
//
#include <hip/hip_runtime.h>
#include <stdint.h>

#define B_    128
#define S_    256
#define EMB_  300
#define HID_  256
#define TAGS_ 50
#define KPAD  320           // EMB padded to multiple of 32
#define NROWS (B_ * S_)     // 32768, row r = s*128 + b
#define GF    (4 * HID_)    // 1024 gate cols per direction
#define NCOLS (2 * GF)      // 2048 (fwd | bwd)

typedef __bf16 bf16x8 __attribute__((ext_vector_type(8)));
typedef float  f32x4  __attribute__((ext_vector_type(4)));
typedef unsigned int u32x4 __attribute__((ext_vector_type(4)));
typedef unsigned long long u64x2 __attribute__((ext_vector_type(2)));

__device__ __forceinline__ unsigned short f2bf(float f) {
    unsigned int u = __float_as_uint(f);
    unsigned int r = (u + 0x7fffu + ((u >> 16) & 1u)) >> 16;  // RNE
    return (unsigned short)r;
}
__device__ __forceinline__ bf16x8 ldb8(const unsigned short* p) {
    u32x4 v = *reinterpret_cast<const u32x4*>(p);
    return __builtin_bit_cast(bf16x8, v);
}
__device__ __forceinline__ float sigmoidf_fast(float x) {
    return 1.0f / (1.0f + __expf(-x));
}
// element q of an f32x4 without dynamic vector indexing (2 cndmask chains)
__device__ __forceinline__ float selq(f32x4 v, int q) {
    float a = (q & 1) ? v[1] : v[0];
    float b = (q & 1) ? v[3] : v[2];
    return (q & 2) ? b : a;
}
__device__ __forceinline__ float bfext(unsigned long long u, int sh) {
    return __uint_as_float((((unsigned int)(u >> sh)) & 0xffffu) << 16);
}

// ---------------- K0a: embedding gather -> bf16, K-padded -------------------
__global__ void k_gather_x(const int* __restrict__ tokens, const float* __restrict__ emb,
                           unsigned short* __restrict__ X16) {
    int r = blockIdx.x;            // r = s*128 + b
    int k = threadIdx.x;           // 0..319
    int b = r & 127, s = r >> 7;
    int tok = tokens[b * S_ + s];
    float v = (k < EMB_) ? emb[(long)tok * EMB_ + k] : 0.0f;
    X16[(long)r * KPAD + k] = f2bf(v);
}

// ---------------- K0b: Wx (f|b) -> transposed bf16 [2048][320] --------------
__global__ void k_prep_w(const float* __restrict__ Wx_f, const float* __restrict__ Wx_b,
                         unsigned short* __restrict__ W16T) {
    int c = blockIdx.x;            // 0..2047
    int k = threadIdx.x;           // 0..319
    float v = 0.0f;
    if (k < EMB_) v = (c < GF) ? Wx_f[k * GF + c] : Wx_b[k * GF + (c - GF)];
    W16T[c * KPAD + k] = f2bf(v);
}

// ---------------- K0c: Wd -> transposed bf16 [64][512] ----------------------
__global__ void k_prep_wd(const float* __restrict__ Wd, unsigned short* __restrict__ WdT16) {
    int c = blockIdx.x;            // 0..63
    int k = threadIdx.x;           // 0..511
    float v = (c < TAGS_) ? Wd[k * TAGS_ + c] : 0.0f;
    WdT16[c * 512 + k] = f2bf(v);
}

// ---------------- K0d: Wh -> packed bf16 [2 dir][4 sl][256 c][256 k] --------
__global__ void k_prep_wh(const float* __restrict__ Wh_f, const float* __restrict__ Wh_b,
                          unsigned short* __restrict__ WhP) {
    int row = blockIdx.x;          // 0..2047 = (d*4+sl)*256 + c
    int k = threadIdx.x;           // 0..255
    int d = row >> 10, sl = (row >> 8) & 3, c = row & 255;
    int gate = c >> 6, jrel = c & 63;
    const float* Wh = d ? Wh_b : Wh_f;
    WhP[(long)row * 256 + k] = f2bf(Wh[k * GF + gate * HID_ + sl * 64 + jrel]);
}

// ---------------- K0e: Wh gates i,f,o -> fp8 e4m3 [2 dir][3 g][256 j][256 k]-
__global__ void k_prep_wh8(const float* __restrict__ Wh_f, const float* __restrict__ Wh_b,
                           unsigned char* __restrict__ WhP8) {
    int row = blockIdx.x;          // 0..1535 = (d*3+gi)*256 + j
    int k = threadIdx.x;           // 0..255
    int d = row / 768, rr = row - d * 768, gi = rr >> 8, j = rr & 255;
    int ga = (gi == 2) ? 3 : gi;   // i=0, f=1, o=3
    const float* Wh = d ? Wh_b : Wh_f;
    float v = Wh[k * GF + ga * HID_ + j];
    int p = __builtin_amdgcn_cvt_pk_fp8_f32(v, 0.0f, 0, false);
    WhP8[(long)row * 256 + k] = (unsigned char)(p & 0xff);
}

// ---------------- K1: xz = X @ Wx + b  (MFMA, LDS-free) ---------------------
// u64 index = (((s*16 + g16)*16 + u16)*256 + lane*4 + gate, lane = quad*16+l16
__global__ __launch_bounds__(256) void k_gemm_xz(
    const unsigned short* __restrict__ X16, const unsigned short* __restrict__ W16T,
    const float* __restrict__ b_f, const float* __restrict__ b_b,
    unsigned long long* __restrict__ xzP) {
    int w = threadIdx.x >> 6, lane = threadIdx.x & 63;
    int quad = lane >> 4, l16 = lane & 15;
    int m0 = blockIdx.x * 128 + w * 32;
    int n0 = blockIdx.y * 128;
    f32x4 acc[2][8];
#pragma unroll
    for (int mt = 0; mt < 2; ++mt)
#pragma unroll
        for (int nt = 0; nt < 8; ++nt) acc[mt][nt] = (f32x4){0.f, 0.f, 0.f, 0.f};

    int koff = quad * 8;
#pragma unroll
    for (int ks = 0; ks < 10; ++ks) {
        int k0 = ks * 32 + koff;
        bf16x8 a[2], bb[8];
#pragma unroll
        for (int mt = 0; mt < 2; ++mt)
            a[mt] = ldb8(X16 + (long)(m0 + mt * 16 + l16) * KPAD + k0);
#pragma unroll
        for (int nt = 0; nt < 8; ++nt)
            bb[nt] = ldb8(W16T + (long)(n0 + nt * 16 + l16) * KPAD + k0);
#pragma unroll
        for (int mt = 0; mt < 2; ++mt)
#pragma unroll
            for (int nt = 0; nt < 8; ++nt)
                acc[mt][nt] = __builtin_amdgcn_mfma_f32_16x16x32_bf16(a[mt], bb[nt], acc[mt][nt], 0, 0, 0);
    }
    int s = blockIdx.x;            // m>>7
#pragma unroll
    for (int mt = 0; mt < 2; ++mt) {
        int grp = w * 2 + mt;      // (b>>4)
#pragma unroll
        for (int nt = 0; nt < 8; ++nt) {
            int col = n0 + nt * 16 + l16;
            int dir = col >> 10, cc = col & 1023;
            int gate = cc >> 8, j = cc & 255;
            int u16 = j >> 4;
            float bias = dir ? b_b[cc] : b_f[cc];
            unsigned long long pk = 0;
#pragma unroll
            for (int r = 0; r < 4; ++r)
                pk |= (unsigned long long)f2bf(acc[mt][nt][r] + bias) << (16 * r);
            long idx8 = (((long)s * 16 + (dir * 8 + grp)) * 16 + u16) * 256 + lane * 4 + gate;
            xzP[idx8] = pk;
        }
    }
}

// ---------------- K2: bidirectional LSTM recurrence, single-CU chains -------
// 64 blocks = 2 dir x 32 batch-groups(4). 512 threads, 2 waves/SIMD.
// g-gate Wh in LDS (fragment-linear, conflict-free); i/f/o Wh fp8 in pinned
// registers. A rows batch-replicated (row = l16&3) -> every lane gets z for
// all 4 batches from MFMA; quad q handles batch q (even gate distribution,
// no shuffles). One __syncthreads per step; zero cross-CU traffic.
__global__ __launch_bounds__(512, 2) void k_recurrence(
    const unsigned short* __restrict__ WhP, const unsigned char* __restrict__ WhP8,
    const unsigned long long* __restrict__ xzP, unsigned short* __restrict__ hcat16) {
    extern __shared__ unsigned char lds[];
    // LDS map (bytes): [0,131072) whg fragments; [131072,135424) hb (2 bufs x
    // 4 rows x 544 B); [135424,137728) h8 (2 bufs x 4 rows x 288 B).
    const int HB = 131072, H8 = 135424;
    int tid = threadIdx.x;
    int w = tid >> 6, lane = tid & 63, quad = lane >> 4, l16 = lane & 15;
    int blk = blockIdx.x;
    int d = blk >> 5, bg4 = blk & 31;
    int g16 = d * 8 + (bg4 >> 2), kq = bg4 & 3;
    int a3 = l16 & 3;

    // stage g-gate Wh into LDS, fragment-linear: region ((w*2+g2)*8+kt): lane*16
#pragma unroll
    for (int g2 = 0; g2 < 2; ++g2) {
        int j = 16 * (2 * w + g2) + l16;
        int sl = j >> 6, jrel = j & 63;
        const unsigned short* src = WhP + ((long)((d * 4 + sl) * 256 + 128 + jrel)) * 256;
#pragma unroll
        for (int kt = 0; kt < 8; ++kt) {
            u32x4 v = *reinterpret_cast<const u32x4*>(src + kt * 32 + quad * 8);
            *reinterpret_cast<u32x4*>(lds + (((w * 2 + g2) * 8 + kt) * 64 + lane) * 16) = v;
        }
    }
    // i/f/o fp8 weight fragments, pinned so the allocator can't rematerialize
    unsigned long long wh8[3][2][8];
#pragma unroll
    for (int gi = 0; gi < 3; ++gi)
#pragma unroll
        for (int g2 = 0; g2 < 2; ++g2) {
            const unsigned char* wp8 =
                WhP8 + ((long)((d * 3 + gi) * 256 + (w * 2 + g2) * 16 + l16)) * 256;
#pragma unroll
            for (int kt = 0; kt < 8; ++kt) {
                unsigned long long v = *reinterpret_cast<const unsigned long long*>(wp8 + kt * 32 + quad * 8);
                asm volatile("" : "+v"(v));
                wh8[gi][g2][kt] = v;
            }
        }
    __syncthreads();

    float c2[2] = {0.f, 0.f};
    int shq = 16 * quad;

    for (int t = 0; t < 256; ++t) {
        int s = d ? (255 - t) : t;
        int pb = t & 1, cb = pb ^ 1;
        // xz prefetch: 4 u64 (gates i,f,g,o) per g2, all quads same address
        unsigned long long xz[2][4];
#pragma unroll
        for (int g2 = 0; g2 < 2; ++g2) {
            const unsigned long long* p =
                xzP + ((((long)s * 16 + g16) * 16 + (2 * w + g2)) * 256 + (kq * 16 + l16) * 4);
            u64x2 aa = *reinterpret_cast<const u64x2*>(p);
            u64x2 bb = *reinterpret_cast<const u64x2*>(p + 2);
            xz[g2][0] = aa[0]; xz[g2][1] = aa[1]; xz[g2][2] = bb[0]; xz[g2][3] = bb[1];
        }
        f32x4 acc[2][4];
#pragma unroll
        for (int g2 = 0; g2 < 2; ++g2)
#pragma unroll
            for (int ga = 0; ga < 4; ++ga) acc[g2][ga] = (f32x4){0.f, 0.f, 0.f, 0.f};

        if (t > 0) {
#pragma unroll
            for (int kt = 0; kt < 8; ++kt) {
                // A: batch-replicated rows (row = l16&3); strides 544/288 B => <=2-way conflicts
                bf16x8 A = ldb8(reinterpret_cast<const unsigned short*>(
                    lds + HB + cb * 2176 + a3 * 544 + kt * 64 + quad * 16));
                long A8 = *reinterpret_cast<const long*>(
                    lds + H8 + cb * 1152 + a3 * 288 + kt * 32 + quad * 8);
#pragma unroll
                for (int g2 = 0; g2 < 2; ++g2) {
                    bf16x8 Bg = ldb8(reinterpret_cast<const unsigned short*>(
                        lds + (((w * 2 + g2) * 8 + kt) * 64 + lane) * 16));
                    acc[g2][2] = __builtin_amdgcn_mfma_f32_16x16x32_bf16(A, Bg, acc[g2][2], 0, 0, 0);
                    acc[g2][0] = __builtin_amdgcn_mfma_f32_16x16x32_fp8_fp8(A8, (long)wh8[0][g2][kt], acc[g2][0], 0, 0, 0);
                    acc[g2][1] = __builtin_amdgcn_mfma_f32_16x16x32_fp8_fp8(A8, (long)wh8[1][g2][kt], acc[g2][1], 0, 0, 0);
                    acc[g2][3] = __builtin_amdgcn_mfma_f32_16x16x32_fp8_fp8(A8, (long)wh8[2][g2][kt], acc[g2][3], 0, 0, 0);
                }
            }
        }
        // gates: lane (quad,l16) handles batch=quad, cols 16*(2w+g2)+l16
#pragma unroll
        for (int g2 = 0; g2 < 2; ++g2) {
            float zi = selq(acc[g2][0], quad) + bfext(xz[g2][0], shq);
            float zf = selq(acc[g2][1], quad) + bfext(xz[g2][1], shq);
            float zg = selq(acc[g2][2], quad) + bfext(xz[g2][2], shq);
            float zo = selq(acc[g2][3], quad) + bfext(xz[g2][3], shq);
            float c = sigmoidf_fast(zf) * c2[g2] + sigmoidf_fast(zi) * fmaxf(zg, 0.0f);
            c2[g2] = c;
            float h = sigmoidf_fast(zo) * fmaxf(c, 0.0f);
            int col = 16 * (2 * w + g2) + l16;
            *reinterpret_cast<unsigned short*>(lds + HB + pb * 2176 + quad * 544 + col * 2) = f2bf(h);
            int p8 = __builtin_amdgcn_cvt_pk_fp8_f32(h, h, 0, false);
            *(lds + H8 + pb * 1152 + quad * 288 + col) = (unsigned char)(p8 & 0xff);
        }
        __syncthreads();
        // coalesced hcat write (4 batches x 64 u64)
        if (tid < 256) {
            int b = tid >> 6, c64 = tid & 63;
            unsigned long long hv = *reinterpret_cast<const unsigned long long*>(
                lds + HB + pb * 2176 + b * 544 + c64 * 8);
            *reinterpret_cast<unsigned long long*>(
                hcat16 + ((long)(bg4 * 4 + b) * S_ + s) * 512 + d * HID_ + c64 * 4) = hv;
        }
    }
}

// ---------------- K3: logits = hcat @ Wd  (MFMA, N padded to 64) ------------
__global__ __launch_bounds__(256) void k_gemm_logits(
    const unsigned short* __restrict__ hcat16, const unsigned short* __restrict__ WdT16,
    float* __restrict__ logits) {
    int w = threadIdx.x >> 6, lane = threadIdx.x & 63;
    int quad = lane >> 4, l16 = lane & 15;
    int m0 = blockIdx.x * 128 + w * 32;
    f32x4 acc[2][4];
#pragma unroll
    for (int mt = 0; mt < 2; ++mt)
#pragma unroll
        for (int nt = 0; nt < 4; ++nt) acc[mt][nt] = (f32x4){0.f, 0.f, 0.f, 0.f};
#pragma unroll
    for (int ks = 0; ks < 16; ++ks) {
        int k0 = ks * 32 + quad * 8;
        bf16x8 a[2], bb[4];
#pragma unroll
        for (int mt = 0; mt < 2; ++mt)
            a[mt] = ldb8(hcat16 + (long)(m0 + mt * 16 + l16) * 512 + k0);
#pragma unroll
        for (int nt = 0; nt < 4; ++nt)
            bb[nt] = ldb8(WdT16 + (long)(nt * 16 + l16) * 512 + k0);
#pragma unroll
        for (int mt = 0; mt < 2; ++mt)
#pragma unroll
            for (int nt = 0; nt < 4; ++nt)
                acc[mt][nt] = __builtin_amdgcn_mfma_f32_16x16x32_bf16(a[mt], bb[nt], acc[mt][nt], 0, 0, 0);
    }
#pragma unroll
    for (int mt = 0; mt < 2; ++mt)
#pragma unroll
        for (int nt = 0; nt < 4; ++nt) {
            int rbase = m0 + mt * 16 + quad * 4;
            int col = nt * 16 + l16;
#pragma unroll
            for (int r = 0; r < 4; ++r)
                logits[(long)(rbase + r) * 64 + col] = acc[mt][nt][r];
        }
}

// ---------------- K4: +bd, softmax over 50 tags (one wave per row) ----------
__global__ __launch_bounds__(256) void k_softmax(const float* __restrict__ logits,
                                                 const float* __restrict__ bd,
                                                 float* __restrict__ out) {
    int w = threadIdx.x >> 6, lane = threadIdx.x & 63;
    long r = (long)blockIdx.x * 4 + w;
    float x = (lane < TAGS_) ? logits[r * 64 + lane] + bd[lane] : -3.0e38f;
    float m = x;
#pragma unroll
    for (int off = 32; off >= 1; off >>= 1) m = fmaxf(m, __shfl_xor(m, off, 64));
    float e = (lane < TAGS_) ? __expf(x - m) : 0.0f;
    float ssum = e;
#pragma unroll
    for (int off = 32; off >= 1; off >>= 1) ssum += __shfl_xor(ssum, off, 64);
    if (lane < TAGS_) out[r * TAGS_ + lane] = e / ssum;
}

extern "C" void kernel_launch(void* const* d_in, const int* in_sizes, int n_in,
                              void* d_out, int out_size, void* d_ws, size_t ws_size,
                              hipStream_t stream) {
    (void)in_sizes; (void)n_in; (void)out_size; (void)ws_size;
    const int*   tokens = (const int*)  d_in[0];
    const float* emb    = (const float*)d_in[1];
    const float* Wx_f   = (const float*)d_in[2];
    const float* Wh_f   = (const float*)d_in[3];
    const float* b_f    = (const float*)d_in[4];
    const float* Wx_b   = (const float*)d_in[5];
    const float* Wh_b   = (const float*)d_in[6];
    const float* b_b    = (const float*)d_in[7];
    const float* Wd     = (const float*)d_in[8];
    const float* bd     = (const float*)d_in[9];
    float* out = (float*)d_out;

    // workspace layout (bytes): total 190,119,936
    uint8_t* w = (uint8_t*)d_ws;
    unsigned short* X16    = (unsigned short*)(w);                  // 20,971,520 (dead after K1)
    // aliases inside X16's region, used only after K1:
    unsigned short* WhP    = (unsigned short*)(w);                  //  1,048,576
    unsigned char*  WhP8   = (unsigned char*)(w + 1048576);         //    393,216
    unsigned short* W16T   = (unsigned short*)(w + 20971520);       //  1,310,720
    unsigned short* WdT16  = (unsigned short*)(w + 22282240);       //     65,536
    unsigned long long* xzP = (unsigned long long*)(w + 22347776);  // 134,217,728
    unsigned short* hcat16 = (unsigned short*)(w + 156565504);      //  33,554,432
    float*          logits = (float*)(w + 22347776);                // alias xzP (dead after K2)

    k_gather_x  <<<dim3(NROWS),     dim3(KPAD), 0, stream>>>(tokens, emb, X16);
    k_prep_w    <<<dim3(NCOLS),     dim3(KPAD), 0, stream>>>(Wx_f, Wx_b, W16T);
    k_prep_wd   <<<dim3(64),        dim3(512),  0, stream>>>(Wd, WdT16);
    k_gemm_xz   <<<dim3(256, 16),   dim3(256),  0, stream>>>(X16, W16T, b_f, b_b, xzP);
    // X16 region now dead -> build WhP / WhP8 in it
    k_prep_wh   <<<dim3(2048),      dim3(256),  0, stream>>>(Wh_f, Wh_b, WhP);
    k_prep_wh8  <<<dim3(1536),      dim3(256),  0, stream>>>(Wh_f, Wh_b, WhP8);
    k_recurrence<<<dim3(64),        dim3(512),  137728, stream>>>(WhP, WhP8, xzP, hcat16);
    k_gemm_logits<<<dim3(256),      dim3(256),  0, stream>>>(hcat16, WdT16, logits);
    k_softmax   <<<dim3(NROWS / 4), dim3(256),  0, stream>>>(logits, bd, out);
}

// Round 8
// 774.411 us; speedup vs baseline: 1.6420x; 1.1117x over previous
//
#include <hip/hip_runtime.h>
#include <stdint.h>

#define B_    128
#define S_    256
#define EMB_  300
#define HID_  256
#define TAGS_ 50
#define KPAD  320           // EMB padded to multiple of 32
#define NROWS (B_ * S_)     // 32768, row r = s*128 + b
#define GF    (4 * HID_)    // 1024 gate cols per direction
#define NCOLS (2 * GF)      // 2048 (fwd | bwd)

typedef __bf16 bf16x8 __attribute__((ext_vector_type(8)));
typedef float  f32x4  __attribute__((ext_vector_type(4)));
typedef unsigned int u32x4 __attribute__((ext_vector_type(4)));
typedef unsigned long long u64x2 __attribute__((ext_vector_type(2)));

__device__ __forceinline__ unsigned short f2bf(float f) {
    unsigned int u = __float_as_uint(f);
    unsigned int r = (u + 0x7fffu + ((u >> 16) & 1u)) >> 16;  // RNE
    return (unsigned short)r;
}
__device__ __forceinline__ bf16x8 ldb8(const unsigned short* p) {
    u32x4 v = *reinterpret_cast<const u32x4*>(p);
    return __builtin_bit_cast(bf16x8, v);
}
__device__ __forceinline__ float sigmoidf_fast(float x) {
    return 1.0f / (1.0f + __expf(-x));
}
// element q of an f32x4 without dynamic vector indexing (2 cndmask chains)
__device__ __forceinline__ float selq(f32x4 v, int q) {
    float a = (q & 1) ? v[1] : v[0];
    float b = (q & 1) ? v[3] : v[2];
    return (q & 2) ? b : a;
}
__device__ __forceinline__ float bfext(unsigned long long u, int sh) {
    return __uint_as_float((((unsigned int)(u >> sh)) & 0xffffu) << 16);
}

// ---------------- K0a: embedding gather -> bf16, K-padded -------------------
__global__ void k_gather_x(const int* __restrict__ tokens, const float* __restrict__ emb,
                           unsigned short* __restrict__ X16) {
    int r = blockIdx.x;            // r = s*128 + b
    int k = threadIdx.x;           // 0..319
    int b = r & 127, s = r >> 7;
    int tok = tokens[b * S_ + s];
    float v = (k < EMB_) ? emb[(long)tok * EMB_ + k] : 0.0f;
    X16[(long)r * KPAD + k] = f2bf(v);
}

// ---------------- K0b: Wx (f|b) -> transposed bf16 [2048][320] --------------
__global__ void k_prep_w(const float* __restrict__ Wx_f, const float* __restrict__ Wx_b,
                         unsigned short* __restrict__ W16T) {
    int c = blockIdx.x;            // 0..2047
    int k = threadIdx.x;           // 0..319
    float v = 0.0f;
    if (k < EMB_) v = (c < GF) ? Wx_f[k * GF + c] : Wx_b[k * GF + (c - GF)];
    W16T[c * KPAD + k] = f2bf(v);
}

// ---------------- K0c: Wd -> transposed bf16 [64][512] ----------------------
__global__ void k_prep_wd(const float* __restrict__ Wd, unsigned short* __restrict__ WdT16) {
    int c = blockIdx.x;            // 0..63
    int k = threadIdx.x;           // 0..511
    float v = (c < TAGS_) ? Wd[k * TAGS_ + c] : 0.0f;
    WdT16[c * 512 + k] = f2bf(v);
}

// ---------------- K0d: Wh -> packed bf16 [2 dir][4 sl][256 c][256 k] --------
__global__ void k_prep_wh(const float* __restrict__ Wh_f, const float* __restrict__ Wh_b,
                          unsigned short* __restrict__ WhP) {
    int row = blockIdx.x;          // 0..2047 = (d*4+sl)*256 + c
    int k = threadIdx.x;           // 0..255
    int d = row >> 10, sl = (row >> 8) & 3, c = row & 255;
    int gate = c >> 6, jrel = c & 63;
    const float* Wh = d ? Wh_b : Wh_f;
    WhP[(long)row * 256 + k] = f2bf(Wh[k * GF + gate * HID_ + sl * 64 + jrel]);
}

// ---------------- K0e: Wh gates i,f,o -> fp8 e4m3 [2 dir][3 g][256 j][256 k]-
__global__ void k_prep_wh8(const float* __restrict__ Wh_f, const float* __restrict__ Wh_b,
                           unsigned char* __restrict__ WhP8) {
    int row = blockIdx.x;          // 0..1535 = (d*3+gi)*256 + j
    int k = threadIdx.x;           // 0..255
    int d = row / 768, rr = row - d * 768, gi = rr >> 8, j = rr & 255;
    int ga = (gi == 2) ? 3 : gi;   // i=0, f=1, o=3
    const float* Wh = d ? Wh_b : Wh_f;
    float v = Wh[k * GF + ga * HID_ + j];
    int p = __builtin_amdgcn_cvt_pk_fp8_f32(v, 0.0f, 0, false);
    WhP8[(long)row * 256 + k] = (unsigned char)(p & 0xff);
}

// ---------------- K1: xz = X @ Wx + b  (MFMA, LDS-free) ---------------------
// u64 index = (((s*16 + g16)*16 + u16)*256 + lane*4 + gate, lane = quad*16+l16
__global__ __launch_bounds__(256) void k_gemm_xz(
    const unsigned short* __restrict__ X16, const unsigned short* __restrict__ W16T,
    const float* __restrict__ b_f, const float* __restrict__ b_b,
    unsigned long long* __restrict__ xzP) {
    int w = threadIdx.x >> 6, lane = threadIdx.x & 63;
    int quad = lane >> 4, l16 = lane & 15;
    int m0 = blockIdx.x * 128 + w * 32;
    int n0 = blockIdx.y * 128;
    f32x4 acc[2][8];
#pragma unroll
    for (int mt = 0; mt < 2; ++mt)
#pragma unroll
        for (int nt = 0; nt < 8; ++nt) acc[mt][nt] = (f32x4){0.f, 0.f, 0.f, 0.f};

    int koff = quad * 8;
#pragma unroll
    for (int ks = 0; ks < 10; ++ks) {
        int k0 = ks * 32 + koff;
        bf16x8 a[2], bb[8];
#pragma unroll
        for (int mt = 0; mt < 2; ++mt)
            a[mt] = ldb8(X16 + (long)(m0 + mt * 16 + l16) * KPAD + k0);
#pragma unroll
        for (int nt = 0; nt < 8; ++nt)
            bb[nt] = ldb8(W16T + (long)(n0 + nt * 16 + l16) * KPAD + k0);
#pragma unroll
        for (int mt = 0; mt < 2; ++mt)
#pragma unroll
            for (int nt = 0; nt < 8; ++nt)
                acc[mt][nt] = __builtin_amdgcn_mfma_f32_16x16x32_bf16(a[mt], bb[nt], acc[mt][nt], 0, 0, 0);
    }
    int s = blockIdx.x;            // m>>7
#pragma unroll
    for (int mt = 0; mt < 2; ++mt) {
        int grp = w * 2 + mt;      // (b>>4)
#pragma unroll
        for (int nt = 0; nt < 8; ++nt) {
            int col = n0 + nt * 16 + l16;
            int dir = col >> 10, cc = col & 1023;
            int gate = cc >> 8, j = cc & 255;
            int u16 = j >> 4;
            float bias = dir ? b_b[cc] : b_f[cc];
            unsigned long long pk = 0;
#pragma unroll
            for (int r = 0; r < 4; ++r)
                pk |= (unsigned long long)f2bf(acc[mt][nt][r] + bias) << (16 * r);
            long idx8 = (((long)s * 16 + (dir * 8 + grp)) * 16 + u16) * 256 + lane * 4 + gate;
            xzP[idx8] = pk;
        }
    }
}

// ---------------- K2: bidirectional LSTM recurrence, single-CU chains -------
// 64 blocks = 2 dir x 32 batch-groups(4). 512 threads, 2 waves/SIMD.
// ALL Wh weights register-pinned (g in bf16: 64 VGPR; i/f/o in fp8: 96 VGPR;
// opaque-asm pin blocks rematerialization — AGPR placement is fine, MFMA
// reads AGPRs directly). LDS holds ONLY the h double-buffers (6.6 KB), so
// per-step LDS traffic is just the A fragments (~100 KB/CU vs round-7's
// 229 KB incl. weights). One __syncthreads per step; zero cross-CU traffic.
__global__ __launch_bounds__(512, 2) void k_recurrence(
    const unsigned short* __restrict__ WhP, const unsigned char* __restrict__ WhP8,
    const unsigned long long* __restrict__ xzP, unsigned short* __restrict__ hcat16) {
    // LDS map (bytes): [0,4352) hb (2 bufs x 4 rows x 544 B);
    //                  [4352,6656) h8 (2 bufs x 4 rows x 288 B).
    __shared__ __align__(16) unsigned char lds[6656];
    const int HB = 0, H8 = 4352;
    int tid = threadIdx.x;
    int w = tid >> 6, lane = tid & 63, quad = lane >> 4, l16 = lane & 15;
    int blk = blockIdx.x;
    int d = blk >> 5, bg4 = blk & 31;
    int g16 = d * 8 + (bg4 >> 2), kq = bg4 & 3;
    int a3 = l16 & 3;

    // g-gate bf16 weight fragments, register-pinned (64 VGPR)
    u32x4 whg[2][8];
#pragma unroll
    for (int g2 = 0; g2 < 2; ++g2) {
        int j = 16 * (2 * w + g2) + l16;
        int sl = j >> 6, jrel = j & 63;
        const unsigned short* src = WhP + ((long)((d * 4 + sl) * 256 + 128 + jrel)) * 256;
#pragma unroll
        for (int kt = 0; kt < 8; ++kt) {
            u32x4 v = *reinterpret_cast<const u32x4*>(src + kt * 32 + quad * 8);
            asm volatile("" : "+v"(v));
            whg[g2][kt] = v;
        }
    }
    // i/f/o fp8 weight fragments, register-pinned (96 VGPR)
    unsigned long long wh8[3][2][8];
#pragma unroll
    for (int gi = 0; gi < 3; ++gi)
#pragma unroll
        for (int g2 = 0; g2 < 2; ++g2) {
            const unsigned char* wp8 =
                WhP8 + ((long)((d * 3 + gi) * 256 + (w * 2 + g2) * 16 + l16)) * 256;
#pragma unroll
            for (int kt = 0; kt < 8; ++kt) {
                unsigned long long v = *reinterpret_cast<const unsigned long long*>(wp8 + kt * 32 + quad * 8);
                asm volatile("" : "+v"(v));
                wh8[gi][g2][kt] = v;
            }
        }

    float c2[2] = {0.f, 0.f};
    int shq = 16 * quad;

    for (int t = 0; t < 256; ++t) {
        int s = d ? (255 - t) : t;
        int pb = t & 1, cb = pb ^ 1;
        // xz prefetch: 4 u64 (gates i,f,g,o) per g2 (quads share addresses)
        unsigned long long xz[2][4];
#pragma unroll
        for (int g2 = 0; g2 < 2; ++g2) {
            const unsigned long long* p =
                xzP + ((((long)s * 16 + g16) * 16 + (2 * w + g2)) * 256 + (kq * 16 + l16) * 4);
            u64x2 aa = *reinterpret_cast<const u64x2*>(p);
            u64x2 bb = *reinterpret_cast<const u64x2*>(p + 2);
            xz[g2][0] = aa[0]; xz[g2][1] = aa[1]; xz[g2][2] = bb[0]; xz[g2][3] = bb[1];
        }
        f32x4 acc[2][4];
#pragma unroll
        for (int g2 = 0; g2 < 2; ++g2)
#pragma unroll
            for (int ga = 0; ga < 4; ++ga) acc[g2][ga] = (f32x4){0.f, 0.f, 0.f, 0.f};

        if (t > 0) {
#pragma unroll
            for (int kt = 0; kt < 8; ++kt) {
                // A: batch-replicated rows (row = l16&3); strides 544/288 B
                bf16x8 A = ldb8(reinterpret_cast<const unsigned short*>(
                    lds + HB + cb * 2176 + a3 * 544 + kt * 64 + quad * 16));
                long A8 = *reinterpret_cast<const long*>(
                    lds + H8 + cb * 1152 + a3 * 288 + kt * 32 + quad * 8);
#pragma unroll
                for (int g2 = 0; g2 < 2; ++g2) {
                    bf16x8 Bg = __builtin_bit_cast(bf16x8, whg[g2][kt]);
                    acc[g2][2] = __builtin_amdgcn_mfma_f32_16x16x32_bf16(A, Bg, acc[g2][2], 0, 0, 0);
                    acc[g2][0] = __builtin_amdgcn_mfma_f32_16x16x32_fp8_fp8(A8, (long)wh8[0][g2][kt], acc[g2][0], 0, 0, 0);
                    acc[g2][1] = __builtin_amdgcn_mfma_f32_16x16x32_fp8_fp8(A8, (long)wh8[1][g2][kt], acc[g2][1], 0, 0, 0);
                    acc[g2][3] = __builtin_amdgcn_mfma_f32_16x16x32_fp8_fp8(A8, (long)wh8[2][g2][kt], acc[g2][3], 0, 0, 0);
                }
            }
        }
        // gates: lane (quad,l16) handles batch=quad, cols 16*(2w+g2)+l16
#pragma unroll
        for (int g2 = 0; g2 < 2; ++g2) {
            float zi = selq(acc[g2][0], quad) + bfext(xz[g2][0], shq);
            float zf = selq(acc[g2][1], quad) + bfext(xz[g2][1], shq);
            float zg = selq(acc[g2][2], quad) + bfext(xz[g2][2], shq);
            float zo = selq(acc[g2][3], quad) + bfext(xz[g2][3], shq);
            float c = sigmoidf_fast(zf) * c2[g2] + sigmoidf_fast(zi) * fmaxf(zg, 0.0f);
            c2[g2] = c;
            float h = sigmoidf_fast(zo) * fmaxf(c, 0.0f);
            int col = 16 * (2 * w + g2) + l16;
            *reinterpret_cast<unsigned short*>(lds + HB + pb * 2176 + quad * 544 + col * 2) = f2bf(h);
            int p8 = __builtin_amdgcn_cvt_pk_fp8_f32(h, h, 0, false);
            *(lds + H8 + pb * 1152 + quad * 288 + col) = (unsigned char)(p8 & 0xff);
        }
        __syncthreads();
        // coalesced hcat write (4 batches x 64 u64)
        if (tid < 256) {
            int b = tid >> 6, c64 = tid & 63;
            unsigned long long hv = *reinterpret_cast<const unsigned long long*>(
                lds + HB + pb * 2176 + b * 544 + c64 * 8);
            *reinterpret_cast<unsigned long long*>(
                hcat16 + ((long)(bg4 * 4 + b) * S_ + s) * 512 + d * HID_ + c64 * 4) = hv;
        }
    }
}

// ---------------- K3: logits = hcat @ Wd  (MFMA, N padded to 64) ------------
__global__ __launch_bounds__(256) void k_gemm_logits(
    const unsigned short* __restrict__ hcat16, const unsigned short* __restrict__ WdT16,
    float* __restrict__ logits) {
    int w = threadIdx.x >> 6, lane = threadIdx.x & 63;
    int quad = lane >> 4, l16 = lane & 15;
    int m0 = blockIdx.x * 128 + w * 32;
    f32x4 acc[2][4];
#pragma unroll
    for (int mt = 0; mt < 2; ++mt)
#pragma unroll
        for (int nt = 0; nt < 4; ++nt) acc[mt][nt] = (f32x4){0.f, 0.f, 0.f, 0.f};
#pragma unroll
    for (int ks = 0; ks < 16; ++ks) {
        int k0 = ks * 32 + quad * 8;
        bf16x8 a[2], bb[4];
#pragma unroll
        for (int mt = 0; mt < 2; ++mt)
            a[mt] = ldb8(hcat16 + (long)(m0 + mt * 16 + l16) * 512 + k0);
#pragma unroll
        for (int nt = 0; nt < 4; ++nt)
            bb[nt] = ldb8(WdT16 + (long)(nt * 16 + l16) * 512 + k0);
#pragma unroll
        for (int mt = 0; mt < 2; ++mt)
#pragma unroll
            for (int nt = 0; nt < 4; ++nt)
                acc[mt][nt] = __builtin_amdgcn_mfma_f32_16x16x32_bf16(a[mt], bb[nt], acc[mt][nt], 0, 0, 0);
    }
#pragma unroll
    for (int mt = 0; mt < 2; ++mt)
#pragma unroll
        for (int nt = 0; nt < 4; ++nt) {
            int rbase = m0 + mt * 16 + quad * 4;
            int col = nt * 16 + l16;
#pragma unroll
            for (int r = 0; r < 4; ++r)
                logits[(long)(rbase + r) * 64 + col] = acc[mt][nt][r];
        }
}

// ---------------- K4: +bd, softmax over 50 tags (one wave per row) ----------
__global__ __launch_bounds__(256) void k_softmax(const float* __restrict__ logits,
                                                 const float* __restrict__ bd,
                                                 float* __restrict__ out) {
    int w = threadIdx.x >> 6, lane = threadIdx.x & 63;
    long r = (long)blockIdx.x * 4 + w;
    float x = (lane < TAGS_) ? logits[r * 64 + lane] + bd[lane] : -3.0e38f;
    float m = x;
#pragma unroll
    for (int off = 32; off >= 1; off >>= 1) m = fmaxf(m, __shfl_xor(m, off, 64));
    float e = (lane < TAGS_) ? __expf(x - m) : 0.0f;
    float ssum = e;
#pragma unroll
    for (int off = 32; off >= 1; off >>= 1) ssum += __shfl_xor(ssum, off, 64);
    if (lane < TAGS_) out[r * TAGS_ + lane] = e / ssum;
}

extern "C" void kernel_launch(void* const* d_in, const int* in_sizes, int n_in,
                              void* d_out, int out_size, void* d_ws, size_t ws_size,
                              hipStream_t stream) {
    (void)in_sizes; (void)n_in; (void)out_size; (void)ws_size;
    const int*   tokens = (const int*)  d_in[0];
    const float* emb    = (const float*)d_in[1];
    const float* Wx_f   = (const float*)d_in[2];
    const float* Wh_f   = (const float*)d_in[3];
    const float* b_f    = (const float*)d_in[4];
    const float* Wx_b   = (const float*)d_in[5];
    const float* Wh_b   = (const float*)d_in[6];
    const float* b_b    = (const float*)d_in[7];
    const float* Wd     = (const float*)d_in[8];
    const float* bd     = (const float*)d_in[9];
    float* out = (float*)d_out;

    // workspace layout (bytes): total 190,119,936
    uint8_t* w = (uint8_t*)d_ws;
    unsigned short* X16    = (unsigned short*)(w);                  // 20,971,520 (dead after K1)
    // aliases inside X16's region, used only after K1:
    unsigned short* WhP    = (unsigned short*)(w);                  //  1,048,576
    unsigned char*  WhP8   = (unsigned char*)(w + 1048576);         //    393,216
    unsigned short* W16T   = (unsigned short*)(w + 20971520);       //  1,310,720
    unsigned short* WdT16  = (unsigned short*)(w + 22282240);       //     65,536
    unsigned long long* xzP = (unsigned long long*)(w + 22347776);  // 134,217,728
    unsigned short* hcat16 = (unsigned short*)(w + 156565504);      //  33,554,432
    float*          logits = (float*)(w + 22347776);                // alias xzP (dead after K2)

    k_gather_x  <<<dim3(NROWS),     dim3(KPAD), 0, stream>>>(tokens, emb, X16);
    k_prep_w    <<<dim3(NCOLS),     dim3(KPAD), 0, stream>>>(Wx_f, Wx_b, W16T);
    k_prep_wd   <<<dim3(64),        dim3(512),  0, stream>>>(Wd, WdT16);
    k_gemm_xz   <<<dim3(256, 16),   dim3(256),  0, stream>>>(X16, W16T, b_f, b_b, xzP);
    // X16 region now dead -> build WhP / WhP8 in it
    k_prep_wh   <<<dim3(2048),      dim3(256),  0, stream>>>(Wh_f, Wh_b, WhP);
    k_prep_wh8  <<<dim3(1536),      dim3(256),  0, stream>>>(Wh_f, Wh_b, WhP8);
    k_recurrence<<<dim3(64),        dim3(512),  0, stream>>>(WhP, WhP8, xzP, hcat16);
    k_gemm_logits<<<dim3(256),      dim3(256),  0, stream>>>(hcat16, WdT16, logits);
    k_softmax   <<<dim3(NROWS / 4), dim3(256),  0, stream>>>(logits, bd, out);
}

// Round 9
// 677.627 us; speedup vs baseline: 1.8765x; 1.1428x over previous
//
#include <hip/hip_runtime.h>
#include <stdint.h>

#define B_    128
#define S_    256
#define EMB_  300
#define HID_  256
#define TAGS_ 50
#define KPAD  320           // EMB padded to multiple of 32
#define NROWS (B_ * S_)     // 32768, row r = s*128 + b
#define GF    (4 * HID_)    // 1024 gate cols per direction
#define NCOLS (2 * GF)      // 2048 (fwd | bwd)

typedef __bf16 bf16x8 __attribute__((ext_vector_type(8)));
typedef float  f32x4  __attribute__((ext_vector_type(4)));
typedef unsigned int u32x4 __attribute__((ext_vector_type(4)));
typedef unsigned long long u64x2 __attribute__((ext_vector_type(2)));
typedef int    i32x8  __attribute__((ext_vector_type(8)));

__device__ __forceinline__ unsigned short f2bf(float f) {
    unsigned int u = __float_as_uint(f);
    unsigned int r = (u + 0x7fffu + ((u >> 16) & 1u)) >> 16;  // RNE
    return (unsigned short)r;
}
__device__ __forceinline__ bf16x8 ldb8(const unsigned short* p) {
    u32x4 v = *reinterpret_cast<const u32x4*>(p);
    return __builtin_bit_cast(bf16x8, v);
}
__device__ __forceinline__ float sigmoidf_fast(float x) {
    return 1.0f / (1.0f + __expf(-x));
}
// element q of an f32x4 without dynamic vector indexing (2 cndmask chains)
__device__ __forceinline__ float selq(f32x4 v, int q) {
    float a = (q & 1) ? v[1] : v[0];
    float b = (q & 1) ? v[3] : v[2];
    return (q & 2) ? b : a;
}
__device__ __forceinline__ float bfext(unsigned long long u, int sh) {
    return __uint_as_float((((unsigned int)(u >> sh)) & 0xffffu) << 16);
}

// ---------------- K0a: embedding gather -> bf16, K-padded -------------------
__global__ void k_gather_x(const int* __restrict__ tokens, const float* __restrict__ emb,
                           unsigned short* __restrict__ X16) {
    int r = blockIdx.x;            // r = s*128 + b
    int k = threadIdx.x;           // 0..319
    int b = r & 127, s = r >> 7;
    int tok = tokens[b * S_ + s];
    float v = (k < EMB_) ? emb[(long)tok * EMB_ + k] : 0.0f;
    X16[(long)r * KPAD + k] = f2bf(v);
}

// ---------------- K0b: Wx (f|b) -> transposed bf16 [2048][320] --------------
__global__ void k_prep_w(const float* __restrict__ Wx_f, const float* __restrict__ Wx_b,
                         unsigned short* __restrict__ W16T) {
    int c = blockIdx.x;            // 0..2047
    int k = threadIdx.x;           // 0..319
    float v = 0.0f;
    if (k < EMB_) v = (c < GF) ? Wx_f[k * GF + c] : Wx_b[k * GF + (c - GF)];
    W16T[c * KPAD + k] = f2bf(v);
}

// ---------------- K0c: Wd -> transposed bf16 [64][512] ----------------------
__global__ void k_prep_wd(const float* __restrict__ Wd, unsigned short* __restrict__ WdT16) {
    int c = blockIdx.x;            // 0..63
    int k = threadIdx.x;           // 0..511
    float v = (c < TAGS_) ? Wd[k * TAGS_ + c] : 0.0f;
    WdT16[c * 512 + k] = f2bf(v);
}

// ---------------- K0d: Wh -> packed bf16 [2 dir][4 sl][256 c][256 k] --------
__global__ void k_prep_wh(const float* __restrict__ Wh_f, const float* __restrict__ Wh_b,
                          unsigned short* __restrict__ WhP) {
    int row = blockIdx.x;          // 0..2047 = (d*4+sl)*256 + c
    int k = threadIdx.x;           // 0..255
    int d = row >> 10, sl = (row >> 8) & 3, c = row & 255;
    int gate = c >> 6, jrel = c & 63;
    const float* Wh = d ? Wh_b : Wh_f;
    WhP[(long)row * 256 + k] = f2bf(Wh[k * GF + gate * HID_ + sl * 64 + jrel]);
}

// ---------------- K0e: Wh gates i,f,o -> fp8 e4m3 [2 dir][3 g][256 j][256 k]-
__global__ void k_prep_wh8(const float* __restrict__ Wh_f, const float* __restrict__ Wh_b,
                           unsigned char* __restrict__ WhP8) {
    int row = blockIdx.x;          // 0..1535 = (d*3+gi)*256 + j
    int k = threadIdx.x;           // 0..255
    int d = row / 768, rr = row - d * 768, gi = rr >> 8, j = rr & 255;
    int ga = (gi == 2) ? 3 : gi;   // i=0, f=1, o=3
    const float* Wh = d ? Wh_b : Wh_f;
    float v = Wh[k * GF + ga * HID_ + j];
    int p = __builtin_amdgcn_cvt_pk_fp8_f32(v, 0.0f, 0, false);
    WhP8[(long)row * 256 + k] = (unsigned char)(p & 0xff);
}

// ---------------- K1: xz = X @ Wx + b  (MFMA, LDS-free) ---------------------
// xzP gate-major layout: u64 idx = ((s*16+g16)*64 + gate*16 + u16)*64 + b4*16 + j
// (u64 packs 4 batches b4*4+{0..3} as bf16). Producer stores are 512 B/wave
// contiguous; consumer reads stay 128 B/quad coalesced.
__global__ __launch_bounds__(256) void k_gemm_xz(
    const unsigned short* __restrict__ X16, const unsigned short* __restrict__ W16T,
    const float* __restrict__ b_f, const float* __restrict__ b_b,
    unsigned long long* __restrict__ xzP) {
    int w = threadIdx.x >> 6, lane = threadIdx.x & 63;
    int quad = lane >> 4, l16 = lane & 15;
    int m0 = blockIdx.x * 128 + w * 32;
    int n0 = blockIdx.y * 128;
    f32x4 acc[2][8];
#pragma unroll
    for (int mt = 0; mt < 2; ++mt)
#pragma unroll
        for (int nt = 0; nt < 8; ++nt) acc[mt][nt] = (f32x4){0.f, 0.f, 0.f, 0.f};

    int koff = quad * 8;
#pragma unroll
    for (int ks = 0; ks < 10; ++ks) {
        int k0 = ks * 32 + koff;
        bf16x8 a[2], bb[8];
#pragma unroll
        for (int mt = 0; mt < 2; ++mt)
            a[mt] = ldb8(X16 + (long)(m0 + mt * 16 + l16) * KPAD + k0);
#pragma unroll
        for (int nt = 0; nt < 8; ++nt)
            bb[nt] = ldb8(W16T + (long)(n0 + nt * 16 + l16) * KPAD + k0);
#pragma unroll
        for (int mt = 0; mt < 2; ++mt)
#pragma unroll
            for (int nt = 0; nt < 8; ++nt)
                acc[mt][nt] = __builtin_amdgcn_mfma_f32_16x16x32_bf16(a[mt], bb[nt], acc[mt][nt], 0, 0, 0);
    }
    int s = blockIdx.x;            // m>>7
#pragma unroll
    for (int mt = 0; mt < 2; ++mt) {
        int grp = w * 2 + mt;      // (b>>4)
#pragma unroll
        for (int nt = 0; nt < 8; ++nt) {
            int col = n0 + nt * 16 + l16;
            int dir = col >> 10, cc = col & 1023;
            int gate = cc >> 8, u16 = (cc & 255) >> 4;
            float bias = dir ? b_b[cc] : b_f[cc];
            unsigned long long pk = 0;
#pragma unroll
            for (int r = 0; r < 4; ++r)
                pk |= (unsigned long long)f2bf(acc[mt][nt][r] + bias) << (16 * r);
            long idx8 = ((long)(s * 16 + dir * 8 + grp)) * 4096 +
                        (gate * 16 + u16) * 64 + quad * 16 + l16;
            xzP[idx8] = pk;
        }
    }
}

// ---------------- K2: bidirectional LSTM recurrence, single-CU chains -------
// 64 blocks = 2 dir x 32 batch-groups(4). 512 threads, 2 waves/SIMD.
// Wh register-pinned: g bf16 (64 VGPR), i/f/o fp8 as K=128 scaled-MFMA
// fragments (96 VGPR; scale=1.0 => identical math to plain fp8 at 2x rate,
// 12 instead of 48 MFMA/wave/step). LDS = h double-buffers only. Barrier is
// hand-rolled "s_waitcnt lgkmcnt(0); s_barrier" — NO vmcnt drain, so hcat
// stores (register-direct) and xz prefetch stay in flight across steps.
__global__ __launch_bounds__(512, 2) void k_recurrence(
    const unsigned short* __restrict__ WhP, const unsigned char* __restrict__ WhP8,
    const unsigned long long* __restrict__ xzP, unsigned short* __restrict__ hcat16) {
    __shared__ __align__(16) unsigned char lds[6656];
    const int HB = 0, H8 = 4352;   // hb: 2 x 4 x 544 B; h8: 2 x 4 x 288 B
    int tid = threadIdx.x;
    int w = tid >> 6, lane = tid & 63, quad = lane >> 4, l16 = lane & 15;
    int blk = blockIdx.x;
    int d = blk >> 5, bg4 = blk & 31;
    int g16 = d * 8 + (bg4 >> 2), kq = bg4 & 3;
    int a3 = l16 & 3;

    // g-gate bf16 weight fragments, register-pinned (64 VGPR)
    u32x4 whg[2][8];
#pragma unroll
    for (int g2 = 0; g2 < 2; ++g2) {
        int j = 16 * (2 * w + g2) + l16;
        int sl = j >> 6, jrel = j & 63;
        const unsigned short* src = WhP + ((long)((d * 4 + sl) * 256 + 128 + jrel)) * 256;
#pragma unroll
        for (int kt = 0; kt < 8; ++kt) {
            u32x4 v = *reinterpret_cast<const u32x4*>(src + kt * 32 + quad * 8);
            asm volatile("" : "+v"(v));
            whg[g2][kt] = v;
        }
    }
    // i/f/o fp8 K=128 scaled-MFMA B fragments, register-pinned (96 VGPR)
    // B[k][n=l16], k = quad*32 + byte (32 contiguous bytes per lane)
    i32x8 wh8s[3][2][2];
#pragma unroll
    for (int gi = 0; gi < 3; ++gi)
#pragma unroll
        for (int g2 = 0; g2 < 2; ++g2)
#pragma unroll
            for (int kt2 = 0; kt2 < 2; ++kt2) {
                const unsigned char* wp8 = WhP8 +
                    ((long)((d * 3 + gi) * 256 + 16 * (2 * w + g2) + l16)) * 256 +
                    kt2 * 128 + quad * 32;
                i32x8 v = *reinterpret_cast<const i32x8*>(wp8);
                asm volatile("" : "+v"(v));
                wh8s[gi][g2][kt2] = v;
            }

    float c2[2] = {0.f, 0.f};
    int shq = 16 * quad;

    // preload xz for first step
    unsigned long long xz[2][4];
    {
        int s0 = d ? 255 : 0;
        long base = ((long)(s0 * 16 + g16)) * 4096;
#pragma unroll
        for (int g2 = 0; g2 < 2; ++g2)
#pragma unroll
            for (int ga = 0; ga < 4; ++ga)
                xz[g2][ga] = xzP[base + (ga * 16 + 2 * w + g2) * 64 + kq * 16 + l16];
    }

    for (int t = 0; t < 256; ++t) {
        int s = d ? (255 - t) : t;
        int pb = t & 1, cb = pb ^ 1;
        f32x4 accg[2];
        f32x4 acc8[3][2];
#pragma unroll
        for (int g2 = 0; g2 < 2; ++g2) {
            accg[g2] = (f32x4){0.f, 0.f, 0.f, 0.f};
#pragma unroll
            for (int gi = 0; gi < 3; ++gi) acc8[gi][g2] = (f32x4){0.f, 0.f, 0.f, 0.f};
        }

        if (t > 0) {
#pragma unroll
            for (int kt = 0; kt < 8; ++kt) {
                bf16x8 A = ldb8(reinterpret_cast<const unsigned short*>(
                    lds + HB + cb * 2176 + a3 * 544 + kt * 64 + quad * 16));
#pragma unroll
                for (int g2 = 0; g2 < 2; ++g2)
                    accg[g2] = __builtin_amdgcn_mfma_f32_16x16x32_bf16(
                        A, __builtin_bit_cast(bf16x8, whg[g2][kt]), accg[g2], 0, 0, 0);
            }
#pragma unroll
            for (int kt2 = 0; kt2 < 2; ++kt2) {
                i32x8 A8 = *reinterpret_cast<const i32x8*>(
                    lds + H8 + cb * 1152 + a3 * 288 + kt2 * 128 + quad * 32);
#pragma unroll
                for (int g2 = 0; g2 < 2; ++g2)
#pragma unroll
                    for (int gi = 0; gi < 3; ++gi)
#if __has_builtin(__builtin_amdgcn_mfma_scale_f32_16x16x128_f8f6f4)
                        acc8[gi][g2] = __builtin_amdgcn_mfma_scale_f32_16x16x128_f8f6f4(
                            A8, wh8s[gi][g2][kt2], acc8[gi][g2], 0, 0, 0, 0x7F, 0, 0x7F);
#else
                        acc8[gi][g2] = acc8[gi][g2];  // unreachable on gfx950
#endif
            }
        }
        // extract current-step xz addends, then immediately prefetch next step
        float xa[2][4];
#pragma unroll
        for (int g2 = 0; g2 < 2; ++g2)
#pragma unroll
            for (int ga = 0; ga < 4; ++ga) xa[g2][ga] = bfext(xz[g2][ga], shq);
        int sn = d ? (s ? s - 1 : 0) : (s < 255 ? s + 1 : 255);
        {
            long basen = ((long)(sn * 16 + g16)) * 4096;
#pragma unroll
            for (int g2 = 0; g2 < 2; ++g2)
#pragma unroll
                for (int ga = 0; ga < 4; ++ga)
                    xz[g2][ga] = xzP[basen + (ga * 16 + 2 * w + g2) * 64 + kq * 16 + l16];
        }
        // gates: lane (quad,l16) handles batch = bg4*4+quad, cols 16*(2w+g2)+l16
#pragma unroll
        for (int g2 = 0; g2 < 2; ++g2) {
            float zi = selq(acc8[0][g2], quad) + xa[g2][0];
            float zf = selq(acc8[1][g2], quad) + xa[g2][1];
            float zg = selq(accg[g2],    quad) + xa[g2][2];
            float zo = selq(acc8[2][g2], quad) + xa[g2][3];
            float c = sigmoidf_fast(zf) * c2[g2] + sigmoidf_fast(zi) * fmaxf(zg, 0.0f);
            c2[g2] = c;
            float h = sigmoidf_fast(zo) * fmaxf(c, 0.0f);
            unsigned short hb16 = f2bf(h);
            int col = 16 * (2 * w + g2) + l16;
            *reinterpret_cast<unsigned short*>(lds + HB + pb * 2176 + quad * 544 + col * 2) = hb16;
            int p8 = __builtin_amdgcn_cvt_pk_fp8_f32(h, h, 0, false);
            *(lds + H8 + pb * 1152 + quad * 288 + col) = (unsigned char)(p8 & 0xff);
            // hcat direct from register (fire-and-forget; barrier won't drain it)
            hcat16[((long)(bg4 * 4 + quad) * S_ + s) * 512 + d * HID_ + col] = hb16;
        }
        // LDS-only barrier: no vmcnt drain (global stores/loads stay in flight)
        asm volatile("s_waitcnt lgkmcnt(0)\n\ts_barrier" ::: "memory");
    }
}

// ---------------- K3: logits = hcat @ Wd  (MFMA, N padded to 64) ------------
__global__ __launch_bounds__(256) void k_gemm_logits(
    const unsigned short* __restrict__ hcat16, const unsigned short* __restrict__ WdT16,
    float* __restrict__ logits) {
    int w = threadIdx.x >> 6, lane = threadIdx.x & 63;
    int quad = lane >> 4, l16 = lane & 15;
    int m0 = blockIdx.x * 128 + w * 32;
    f32x4 acc[2][4];
#pragma unroll
    for (int mt = 0; mt < 2; ++mt)
#pragma unroll
        for (int nt = 0; nt < 4; ++nt) acc[mt][nt] = (f32x4){0.f, 0.f, 0.f, 0.f};
#pragma unroll
    for (int ks = 0; ks < 16; ++ks) {
        int k0 = ks * 32 + quad * 8;
        bf16x8 a[2], bb[4];
#pragma unroll
        for (int mt = 0; mt < 2; ++mt)
            a[mt] = ldb8(hcat16 + (long)(m0 + mt * 16 + l16) * 512 + k0);
#pragma unroll
        for (int nt = 0; nt < 4; ++nt)
            bb[nt] = ldb8(WdT16 + (long)(nt * 16 + l16) * 512 + k0);
#pragma unroll
        for (int mt = 0; mt < 2; ++mt)
#pragma unroll
            for (int nt = 0; nt < 4; ++nt)
                acc[mt][nt] = __builtin_amdgcn_mfma_f32_16x16x32_bf16(a[mt], bb[nt], acc[mt][nt], 0, 0, 0);
    }
#pragma unroll
    for (int mt = 0; mt < 2; ++mt)
#pragma unroll
        for (int nt = 0; nt < 4; ++nt) {
            int rbase = m0 + mt * 16 + quad * 4;
            int col = nt * 16 + l16;
#pragma unroll
            for (int r = 0; r < 4; ++r)
                logits[(long)(rbase + r) * 64 + col] = acc[mt][nt][r];
        }
}

// ---------------- K4: +bd, softmax over 50 tags (one wave per row) ----------
__global__ __launch_bounds__(256) void k_softmax(const float* __restrict__ logits,
                                                 const float* __restrict__ bd,
                                                 float* __restrict__ out) {
    int w = threadIdx.x >> 6, lane = threadIdx.x & 63;
    long r = (long)blockIdx.x * 4 + w;
    float x = (lane < TAGS_) ? logits[r * 64 + lane] + bd[lane] : -3.0e38f;
    float m = x;
#pragma unroll
    for (int off = 32; off >= 1; off >>= 1) m = fmaxf(m, __shfl_xor(m, off, 64));
    float e = (lane < TAGS_) ? __expf(x - m) : 0.0f;
    float ssum = e;
#pragma unroll
    for (int off = 32; off >= 1; off >>= 1) ssum += __shfl_xor(ssum, off, 64);
    if (lane < TAGS_) out[r * TAGS_ + lane] = e / ssum;
}

extern "C" void kernel_launch(void* const* d_in, const int* in_sizes, int n_in,
                              void* d_out, int out_size, void* d_ws, size_t ws_size,
                              hipStream_t stream) {
    (void)in_sizes; (void)n_in; (void)out_size; (void)ws_size;
    const int*   tokens = (const int*)  d_in[0];
    const float* emb    = (const float*)d_in[1];
    const float* Wx_f   = (const float*)d_in[2];
    const float* Wh_f   = (const float*)d_in[3];
    const float* b_f    = (const float*)d_in[4];
    const float* Wx_b   = (const float*)d_in[5];
    const float* Wh_b   = (const float*)d_in[6];
    const float* b_b    = (const float*)d_in[7];
    const float* Wd     = (const float*)d_in[8];
    const float* bd     = (const float*)d_in[9];
    float* out = (float*)d_out;

    // workspace layout (bytes): total 190,119,936
    uint8_t* w = (uint8_t*)d_ws;
    unsigned short* X16    = (unsigned short*)(w);                  // 20,971,520 (dead after K1)
    // aliases inside X16's region, used only after K1:
    unsigned short* WhP    = (unsigned short*)(w);                  //  1,048,576
    unsigned char*  WhP8   = (unsigned char*)(w + 1048576);         //    393,216
    unsigned short* W16T   = (unsigned short*)(w + 20971520);       //  1,310,720
    unsigned short* WdT16  = (unsigned short*)(w + 22282240);       //     65,536
    unsigned long long* xzP = (unsigned long long*)(w + 22347776);  // 134,217,728
    unsigned short* hcat16 = (unsigned short*)(w + 156565504);      //  33,554,432
    float*          logits = (float*)(w + 22347776);                // alias xzP (dead after K2)

    k_gather_x  <<<dim3(NROWS),     dim3(KPAD), 0, stream>>>(tokens, emb, X16);
    k_prep_w    <<<dim3(NCOLS),     dim3(KPAD), 0, stream>>>(Wx_f, Wx_b, W16T);
    k_prep_wd   <<<dim3(64),        dim3(512),  0, stream>>>(Wd, WdT16);
    k_gemm_xz   <<<dim3(256, 16),   dim3(256),  0, stream>>>(X16, W16T, b_f, b_b, xzP);
    // X16 region now dead -> build WhP / WhP8 in it
    k_prep_wh   <<<dim3(2048),      dim3(256),  0, stream>>>(Wh_f, Wh_b, WhP);
    k_prep_wh8  <<<dim3(1536),      dim3(256),  0, stream>>>(Wh_f, Wh_b, WhP8);
    k_recurrence<<<dim3(64),        dim3(512),  0, stream>>>(WhP, WhP8, xzP, hcat16);
    k_gemm_logits<<<dim3(256),      dim3(256),  0, stream>>>(hcat16, WdT16, logits);
    k_softmax   <<<dim3(NROWS / 4), dim3(256),  0, stream>>>(logits, bd, out);
}